// Round 2
// baseline (389.385 us; speedup 1.0000x reference)
//
#include <hip/hip_runtime.h>

// CSPN 3x3 propagation, float32.
//   out[b,y,x] = sum_{t=0..8, t=dy*3+dx} k[b,t,y,x] * patch(t)
//   patch(t) = zero-padded input at (y+dy-1, x+dx-1), EXCEPT t==4 (center),
//   which is input0[b,y,x].
//
// Round-4: fix round-3 compile error -- __builtin_nontemporal_* requires a
// native vector type, not HIP's float4 class. Use ext_vector_type(4).
//  - 8 px/thread (two float4 per stream): halves index/addr overhead,
//    doubles independent load streams per wave for the 9 strided tap planes.
//  - nontemporal load on ker/inp0 (zero-reuse, ~300 MB of the 329 MB
//    working set) + nontemporal store on out: keeps L2/L3 free for the
//    input rows which ARE reused 3x across y-neighboring thread rows.
//  - inp stays on the cached path (the only tensor with reuse).
//
// Compulsory traffic: 48 B/px * 6.85 Mpx ~= 329 MB -> ~52 us at 6.3 TB/s.
// The bench's dur_us additionally contains ~300 us of harness re-poison
// fills (two 986 MB fillBufferAligned dispatches at ~150 us each per
// round-2 rocprof) -- not addressable from the kernel.

#define BS 16
#define H  352
#define W  1216
#define HW (H * W)
#define WQ8 (W / 8)   // 152 threads per row

typedef float vfloat4 __attribute__((ext_vector_type(4)));

__global__ __launch_bounds__(256) void cspn_kernel(
    const float* __restrict__ ker,   // [BS, 9, H, W]
    const float* __restrict__ inp,   // [BS, 1, H, W]
    const float* __restrict__ inp0,  // [BS, 1, H, W]
    float* __restrict__ out)         // [BS, 1, H, W]
{
    int tid = blockIdx.x * blockDim.x + threadIdx.x;
    const int total = BS * H * WQ8;
    if (tid >= total) return;

    int xq = tid % WQ8;
    int t  = tid / WQ8;
    int y  = t % H;
    int b  = t / H;
    int x0 = xq * 8;

    // Gather 3 input rows, 10 columns each: input[y+dy-1][x0-1 .. x0+8].
    // Kept pristine -- taps 3 and 5 need the original center row; only
    // tap 4 is replaced (by input0, held separately in cen[]).
    float row[3][10];
    const float* inb = inp + (size_t)b * HW;
#pragma unroll
    for (int dy = 0; dy < 3; ++dy) {
        int yy = y + dy - 1;
        if (yy < 0 || yy >= H) {
#pragma unroll
            for (int c = 0; c < 10; ++c) row[dy][c] = 0.f;
        } else {
            const float* r = inb + (size_t)yy * W + x0;
            vfloat4 v0 = *(const vfloat4*)r;        // cached: reused by y+/-1 rows
            vfloat4 v1 = *(const vfloat4*)(r + 4);
            row[dy][1] = v0.x; row[dy][2] = v0.y;
            row[dy][3] = v0.z; row[dy][4] = v0.w;
            row[dy][5] = v1.x; row[dy][6] = v1.y;
            row[dy][7] = v1.z; row[dy][8] = v1.w;
            row[dy][0] = (x0 > 0)     ? r[-1] : 0.f;
            row[dy][9] = (x0 + 8 < W) ? r[8]  : 0.f;
        }
    }

    // Center tap (tap 4 ONLY) comes from input0. Zero reuse -> nontemporal.
    const float* c0p = inp0 + (size_t)b * HW + (size_t)y * W + x0;
    vfloat4 ca = __builtin_nontemporal_load((const vfloat4*)c0p);
    vfloat4 cb = __builtin_nontemporal_load((const vfloat4*)(c0p + 4));
    float cen[8] = {ca.x, ca.y, ca.z, ca.w, cb.x, cb.y, cb.z, cb.w};

    float acc[8] = {0.f, 0.f, 0.f, 0.f, 0.f, 0.f, 0.f, 0.f};
    const float* kb = ker + (size_t)b * 9 * HW + (size_t)y * W + x0;
#pragma unroll
    for (int t9 = 0; t9 < 9; ++t9) {
        int dy = t9 / 3, dx = t9 % 3;
        const float* kp = kb + (size_t)t9 * HW;
        vfloat4 k0 = __builtin_nontemporal_load((const vfloat4*)kp);
        vfloat4 k1 = __builtin_nontemporal_load((const vfloat4*)(kp + 4));
        float kf[8] = {k0.x, k0.y, k0.z, k0.w, k1.x, k1.y, k1.z, k1.w};
#pragma unroll
        for (int l = 0; l < 8; ++l) {
            float p = (t9 == 4) ? cen[l] : row[dy][dx + l];
            acc[l] = fmaf(kf[l], p, acc[l]);
        }
    }

    float* op = out + (size_t)b * HW + (size_t)y * W + x0;
    vfloat4 o0 = {acc[0], acc[1], acc[2], acc[3]};
    vfloat4 o1 = {acc[4], acc[5], acc[6], acc[7]};
    __builtin_nontemporal_store(o0, (vfloat4*)op);
    __builtin_nontemporal_store(o1, (vfloat4*)(op + 4));
}

extern "C" void kernel_launch(void* const* d_in, const int* in_sizes, int n_in,
                              void* d_out, int out_size, void* d_ws, size_t ws_size,
                              hipStream_t stream) {
    // Kernel tensor is the 9x-sized buffer; remaining two keep dict order:
    // input, then input0.
    int ki = 0;
    for (int i = 1; i < n_in; ++i)
        if (in_sizes[i] > in_sizes[ki]) ki = i;
    int rest[2], nr = 0;
    for (int i = 0; i < n_in; ++i)
        if (i != ki) rest[nr++] = i;

    const float* ker  = (const float*)d_in[ki];
    const float* inp  = (const float*)d_in[rest[0]];
    const float* inp0 = (const float*)d_in[rest[1]];
    float* outp = (float*)d_out;

    const int total = BS * H * WQ8;          // threads, 8 px each
    const int block = 256;
    const int grid  = (total + block - 1) / block;
    cspn_kernel<<<grid, block, 0, stream>>>(ker, inp, inp0, outp);
}

// Round 4
// 368.326 us; speedup vs baseline: 1.0572x; 1.0572x over previous
//
#include <hip/hip_runtime.h>

// CSPN 3x3 propagation, all-float32. Verified-best variant
// (367.4 / 369.0 us measured twice). Round-5: resubmit unchanged —
// round-4 bench was an infra failure (container acquisition), not a result.
//
//   out[b,y,x] = sum_{t=0..8, t=dy*3+dx} k[b,t,y,x] * patch(t)
//   patch(t) = zero-padded input at (y+dy-1, x+dx-1), EXCEPT t==4 (center),
//   which is input0[b,y,x].
//
// input0 feeds ONLY tap 4; taps 3 and 5 read the original input row at
// overlapping x — row[1] stays pristine, center tap uses a separate c0 vec.
//
// Experiment log (why this exact shape):
//  - 4 px/thread, plain cached float4 loads: 367-369 us  <- BEST (this file)
//  - 8 px/thread + nontemporal ker/inp0/out: 389 us      <- REGRESSED.
//    nt hints bought nothing (27 MB inp reuse already absorbed by the
//    256 MB shared L3; nt store lost L2 write-combining) and 8 px/thread
//    raised VGPR pressure, costing latency-hiding occupancy.
//
// Roofline accounting: 48 B/px * 6.85 Mpx ~= 329 MB compulsory -> ~52 us
// at 6.3 TB/s. rocprof shows the timed dur_us additionally contains ~300 us
// of harness re-poison fillBufferAligned dispatches (~986 MB at ~150 us
// each, 82-84% HBM peak) which the kernel cannot affect; cspn_kernel itself
// never cracks the top-5 (i.e. runs < 147 us, est. ~70 us).

#define BS 16
#define H  352
#define W  1216
#define HW (H * W)
#define WQ (W / 4)   // 304

__global__ __launch_bounds__(256) void cspn_kernel(
    const float* __restrict__ ker,   // [BS, 9, H, W]
    const float* __restrict__ inp,   // [BS, 1, H, W]
    const float* __restrict__ inp0,  // [BS, 1, H, W]
    float* __restrict__ out)         // [BS, 1, H, W]
{
    int tid = blockIdx.x * blockDim.x + threadIdx.x;
    const int total = BS * H * WQ;
    if (tid >= total) return;

    int xq = tid % WQ;
    int t  = tid / WQ;
    int y  = t % H;
    int b  = t / H;
    int x0 = xq * 4;

    // Gather 3 input rows, 6 columns each: input[y+dy-1][x0-1 .. x0+4].
    // NEVER overwritten — taps 3 and 5 need the original center row.
    float row[3][6];
    const float* inb = inp + (size_t)b * HW;
#pragma unroll
    for (int dy = 0; dy < 3; ++dy) {
        int yy = y + dy - 1;
        if (yy < 0 || yy >= H) {
#pragma unroll
            for (int c = 0; c < 6; ++c) row[dy][c] = 0.f;
        } else {
            const float* r = inb + (size_t)yy * W + x0;
            float4 v = *(const float4*)r;
            row[dy][1] = v.x; row[dy][2] = v.y;
            row[dy][3] = v.z; row[dy][4] = v.w;
            row[dy][0] = (x0 > 0)     ? r[-1] : 0.f;
            row[dy][5] = (x0 + 4 < W) ? r[4]  : 0.f;
        }
    }

    // Center tap values (tap 4 ONLY) come from input0.
    float4 c0 = *(const float4*)(inp0 + (size_t)b * HW + (size_t)y * W + x0);
    float cen[4] = {c0.x, c0.y, c0.z, c0.w};

    float acc[4] = {0.f, 0.f, 0.f, 0.f};
    const float* kb = ker + (size_t)b * 9 * HW + (size_t)y * W + x0;
#pragma unroll
    for (int t9 = 0; t9 < 9; ++t9) {
        int dy = t9 / 3, dx = t9 % 3;
        float4 kv = *(const float4*)(kb + (size_t)t9 * HW);
        float kf[4] = {kv.x, kv.y, kv.z, kv.w};
#pragma unroll
        for (int l = 0; l < 4; ++l) {
            float p = (t9 == 4) ? cen[l] : row[dy][dx + l];
            acc[l] = fmaf(kf[l], p, acc[l]);
        }
    }

    float4 o = make_float4(acc[0], acc[1], acc[2], acc[3]);
    *(float4*)(out + (size_t)b * HW + (size_t)y * W + x0) = o;
}

extern "C" void kernel_launch(void* const* d_in, const int* in_sizes, int n_in,
                              void* d_out, int out_size, void* d_ws, size_t ws_size,
                              hipStream_t stream) {
    // Kernel tensor is the 9x-sized buffer; remaining two keep dict order:
    // input, then input0.
    int ki = 0;
    for (int i = 1; i < n_in; ++i)
        if (in_sizes[i] > in_sizes[ki]) ki = i;
    int rest[2], nr = 0;
    for (int i = 0; i < n_in; ++i)
        if (i != ki) rest[nr++] = i;

    const float* ker  = (const float*)d_in[ki];
    const float* inp  = (const float*)d_in[rest[0]];
    const float* inp0 = (const float*)d_in[rest[1]];
    float* outp = (float*)d_out;

    const int total = BS * H * WQ;           // threads, 4 px each
    const int block = 256;
    const int grid  = (total + block - 1) / block;
    cspn_kernel<<<grid, block, 0, stream>>>(ker, inp, inp0, outp);
}